// Round 2
// baseline (2325.742 us; speedup 1.0000x reference)
//
#include <hip/hip_runtime.h>

#define N_ACTIVE 200000
#define N_IN 64
#define N_OUT 64
#define K_FILT 27
#define R_PAIRS 100000
#define TOTP (K_FILT * R_PAIRS)     // 2,700,000 pairs
#define RB 128                      // output rows per block
#define NB ((N_ACTIVE + RB - 1) / RB)   // 1563 row-blocks
#define NBUCK (NB * K_FILT)         // 42,201 buckets

// ---------------------------------------------------------------------------
// zero the histogram counters + scatter cursors
// ---------------------------------------------------------------------------
__global__ __launch_bounds__(256) void zero_ints(int* __restrict__ p, int n) {
    int i = blockIdx.x * 256 + threadIdx.x;
    if (i < n) p[i] = 0;
}

// ---------------------------------------------------------------------------
// histogram: bucket = (out_row >> 7) * 27 + k,  k = pair / R
// ---------------------------------------------------------------------------
__global__ __launch_bounds__(256) void hist_kernel(const int* __restrict__ out_idx,
                                                   int* __restrict__ cnt) {
    int p = blockIdx.x * 256 + threadIdx.x;
    if (p >= TOTP) return;
    unsigned k = (unsigned)p / (unsigned)R_PAIRS;
    int b = (out_idx[p] >> 7) * K_FILT + (int)k;
    atomicAdd(&cnt[b], 1);
}

// ---------------------------------------------------------------------------
// exclusive prefix sum over NBUCK counters (single block, chunked Hillis-Steele)
// ---------------------------------------------------------------------------
__global__ __launch_bounds__(1024) void scan_kernel(const int* __restrict__ cnt,
                                                    int* __restrict__ off) {
    __shared__ int s[1024];
    __shared__ int carry;
    int t = threadIdx.x;
    if (t == 0) carry = 0;
    __syncthreads();
    const int NCH = (NBUCK + 1023) / 1024;
    for (int c = 0; c < NCH; ++c) {
        int i = c * 1024 + t;
        int v = (i < NBUCK) ? cnt[i] : 0;
        s[t] = v;
        __syncthreads();
        for (int d = 1; d < 1024; d <<= 1) {
            int x = (t >= d) ? s[t - d] : 0;
            __syncthreads();
            s[t] += x;
            __syncthreads();
        }
        int incl = s[t];
        int tot  = s[1023];
        if (i < NBUCK) off[i] = carry + incl - v;
        __syncthreads();            // all reads of carry/s done
        if (t == 0) carry += tot;
        __syncthreads();            // carry update visible before next chunk
    }
    if (t == 0) off[NBUCK] = carry;
}

// ---------------------------------------------------------------------------
// scatter pair ids into bucket-sorted entry list
// ---------------------------------------------------------------------------
__global__ __launch_bounds__(256) void scatter_kernel(const int* __restrict__ out_idx,
                                                      const int* __restrict__ off,
                                                      int* __restrict__ cursor,
                                                      int* __restrict__ entries) {
    int p = blockIdx.x * 256 + threadIdx.x;
    if (p >= TOTP) return;
    unsigned k = (unsigned)p / (unsigned)R_PAIRS;
    int b = (out_idx[p] >> 7) * K_FILT + (int)k;
    int pos = atomicAdd(&cursor[b], 1);
    entries[off[b] + pos] = p;
}

// ---------------------------------------------------------------------------
// main conv: block owns out rows [b*128, b*128+128). Loop k: stage W[k],
// gather+transpose feature rows of that bucket, 4x4-blocked fp32 matmul,
// scatter-accumulate into LDS out tile (ds_add_f32). No global atomics.
// ---------------------------------------------------------------------------
__global__ __launch_bounds__(256) void conv_kernel(
    const float* __restrict__ feat,     // [N_ACTIVE][64]
    const float* __restrict__ weight,   // [K][64][64]
    const float* __restrict__ bias,     // [64]
    const int* __restrict__ in_idx,     // flat [K*R]
    const int* __restrict__ out_idx,    // flat [K*R]
    const int* __restrict__ off,        // [NBUCK+1]
    const int* __restrict__ entries,    // [TOTP]
    float* __restrict__ out)            // [N_ACTIVE][64]
{
    __shared__ float outT[RB][64];   // 32 KB
    __shared__ float Wlds[64][64];   // 16 KB
    __shared__ float fT[64][64];     // 16 KB (gathered rows, transposed)
    __shared__ int   orow[64];

    const int b = blockIdx.x;
    const int t = threadIdx.x;
    const int rowBase = b * RB;

    // zero out tile: 8 float4 per thread
    {
        float4 z = {0.f, 0.f, 0.f, 0.f};
        float4* o4 = reinterpret_cast<float4*>(&outT[0][0]);
        #pragma unroll
        for (int j = 0; j < 8; ++j) o4[j * 256 + t] = z;
    }

    const int w    = t >> 6;
    const int lane = t & 63;
    const int pg   = lane >> 4;
    const int cg   = lane & 15;
    const int pbase = w * 16 + pg * 4;
    const int cbase = cg * 4;
    const int slot = t >> 2;
    const int q    = t & 3;

    for (int k = 0; k < K_FILT; ++k) {
        int base = off[b * K_FILT + k];
        int cnt  = off[b * K_FILT + k + 1] - base;
        if (cnt == 0) continue;   // uniform across block

        __syncthreads();          // prev-k compute done before Wlds overwrite
        {
            const float4* wsrc = reinterpret_cast<const float4*>(weight + k * 4096);
            float4* wdst = reinterpret_cast<float4*>(&Wlds[0][0]);
            #pragma unroll
            for (int j = 0; j < 4; ++j) wdst[j * 256 + t] = wsrc[j * 256 + t];
        }

        for (int c0 = 0; c0 < cnt; c0 += 64) {
            int nc = cnt - c0; if (nc > 64) nc = 64;
            __syncthreads();      // W staged / prev chunk compute done
            // ---- stage gathered rows transposed, 4 threads per entry ----
            if (slot < nc) {
                int p = entries[base + c0 + slot];
                int ir = in_idx[p];
                if (q == 0) orow[slot] = out_idx[p] - rowBase;
                const float4* fsrc =
                    reinterpret_cast<const float4*>(feat + ir * 64 + q * 16);
                #pragma unroll
                for (int j4 = 0; j4 < 4; ++j4) {
                    float4 v = fsrc[j4];
                    int e = q * 16 + j4 * 4;
                    fT[e + 0][slot] = v.x;
                    fT[e + 1][slot] = v.y;
                    fT[e + 2][slot] = v.z;
                    fT[e + 3][slot] = v.w;
                }
            } else {
                #pragma unroll
                for (int j = 0; j < 16; ++j) fT[q * 16 + j][slot] = 0.f;
                if (q == 0) orow[slot] = 0;   // dummy: acc is 0, adds 0.0
            }
            __syncthreads();

            // ---- 4x4-blocked fp32 matmul ----
            float acc[4][4] = {{0.f}};
            #pragma unroll 8
            for (int i = 0; i < 64; ++i) {
                float4 wv = *reinterpret_cast<const float4*>(&Wlds[i][cbase]);
                float4 fv = *reinterpret_cast<const float4*>(&fT[i][pbase]);
                float fa[4] = {fv.x, fv.y, fv.z, fv.w};
                float wa[4] = {wv.x, wv.y, wv.z, wv.w};
                #pragma unroll
                for (int pi = 0; pi < 4; ++pi)
                    #pragma unroll
                    for (int ci = 0; ci < 4; ++ci)
                        acc[pi][ci] += fa[pi] * wa[ci];
            }

            // ---- scatter into LDS out tile (ds atomics, ~2-way banks) ----
            #pragma unroll
            for (int pi = 0; pi < 4; ++pi) {
                int lr = orow[pbase + pi];
                #pragma unroll
                for (int ci = 0; ci < 4; ++ci)
                    atomicAdd(&outT[lr][cbase + ci], acc[pi][ci]);
            }
        }
    }

    __syncthreads();
    // ---- write out + bias, coalesced float4 ----
    #pragma unroll
    for (int j = 0; j < 8; ++j) {
        int idx = j * 1024 + t * 4;
        int r = idx >> 6, c = idx & 63;
        int gr = rowBase + r;
        if (gr < N_ACTIVE) {
            float4 bv = *reinterpret_cast<const float4*>(&bias[c]);
            float4 v  = *reinterpret_cast<const float4*>(&outT[r][c]);
            float4 s  = {v.x + bv.x, v.y + bv.y, v.z + bv.z, v.w + bv.w};
            *reinterpret_cast<float4*>(&out[gr * 64 + c]) = s;
        }
    }
}

extern "C" void kernel_launch(void* const* d_in, const int* in_sizes, int n_in,
                              void* d_out, int out_size, void* d_ws, size_t ws_size,
                              hipStream_t stream) {
    const float* feat    = (const float*)d_in[0];
    const float* weight  = (const float*)d_in[1];
    const float* bias    = (const float*)d_in[2];
    const int*   in_idx  = (const int*)d_in[3];
    const int*   out_idx = (const int*)d_in[4];
    float* out = (float*)d_out;

    int* cnt     = (int*)d_ws;            // [NBUCK]
    int* cursor  = cnt + NBUCK;           // [NBUCK]
    int* off     = cursor + NBUCK;        // [NBUCK+1]
    int* entries = off + NBUCK + 1;       // [TOTP]

    zero_ints<<<dim3((2 * NBUCK + 255) / 256), dim3(256), 0, stream>>>(cnt, 2 * NBUCK);
    hist_kernel<<<dim3((TOTP + 255) / 256), dim3(256), 0, stream>>>(out_idx, cnt);
    scan_kernel<<<dim3(1), dim3(1024), 0, stream>>>(cnt, off);
    scatter_kernel<<<dim3((TOTP + 255) / 256), dim3(256), 0, stream>>>(out_idx, off, cursor, entries);
    conv_kernel<<<dim3(NB), dim3(256), 0, stream>>>(feat, weight, bias, in_idx, out_idx,
                                                    off, entries, out);
}

// Round 3
// 1293.909 us; speedup vs baseline: 1.7975x; 1.7975x over previous
//
#include <hip/hip_runtime.h>

#define N_ACTIVE 200000
#define N_IN 64
#define N_OUT 64
#define K_FILT 27
#define R_PAIRS 100000
#define TOTP (K_FILT * R_PAIRS)          // 2,700,000
#define RB 128
#define NB ((N_ACTIVE + RB - 1) / RB)    // 1563
#define NBUCK (NB * K_FILT)              // 42,201
#define NSB ((NBUCK + 255) / 256)        // 165

typedef __bf16 bf16x8 __attribute__((ext_vector_type(8)));
typedef float f32x4 __attribute__((ext_vector_type(4)));

// ---------------------------------------------------------------------------
// features fp32 -> bf16 (8 elems/thread, vectorized)
// ---------------------------------------------------------------------------
__global__ __launch_bounds__(256) void convert_feat(const float* __restrict__ f,
                                                    __bf16* __restrict__ fb) {
    int i = blockIdx.x * 256 + threadIdx.x;
    if (i >= N_ACTIVE * N_IN / 8) return;
    const float4* src = reinterpret_cast<const float4*>(f) + 2 * i;
    float4 v0 = src[0], v1 = src[1];
    bf16x8 o;
    o[0] = (__bf16)v0.x; o[1] = (__bf16)v0.y; o[2] = (__bf16)v0.z; o[3] = (__bf16)v0.w;
    o[4] = (__bf16)v1.x; o[5] = (__bf16)v1.y; o[6] = (__bf16)v1.z; o[7] = (__bf16)v1.w;
    reinterpret_cast<bf16x8*>(fb)[i] = o;
}

// ---------------------------------------------------------------------------
// weight fp32 [k][i][o] -> bf16 transposed Wt[k][o][i]
// ---------------------------------------------------------------------------
__global__ __launch_bounds__(256) void convert_wt(const float* __restrict__ wsrc,
                                                  __bf16* __restrict__ wt) {
    int kf = blockIdx.x, t = threadIdx.x;
    const float* wk = wsrc + kf * 4096;
    __bf16* wo = wt + kf * 4096;
    int o = t >> 2, i0 = (t & 3) * 16;
    bf16x8 a, b;
    #pragma unroll
    for (int j = 0; j < 8; ++j) a[j] = (__bf16)wk[(i0 + j) * 64 + o];
    #pragma unroll
    for (int j = 0; j < 8; ++j) b[j] = (__bf16)wk[(i0 + 8 + j) * 64 + o];
    *reinterpret_cast<bf16x8*>(wo + o * 64 + i0) = a;
    *reinterpret_cast<bf16x8*>(wo + o * 64 + i0 + 8) = b;
}

__global__ __launch_bounds__(256) void zero_ints(int* __restrict__ p, int n) {
    int i = blockIdx.x * 256 + threadIdx.x;
    if (i < n) p[i] = 0;
}

__global__ __launch_bounds__(256) void hist_kernel(const int* __restrict__ out_idx,
                                                   int* __restrict__ cnt) {
    int p = blockIdx.x * 256 + threadIdx.x;
    if (p >= TOTP) return;
    unsigned k = (unsigned)p / (unsigned)R_PAIRS;
    int b = (out_idx[p] >> 7) * K_FILT + (int)k;
    atomicAdd(&cnt[b], 1);
}

// ---- hierarchical exclusive scan over NBUCK counters (3 small kernels) ----
__global__ __launch_bounds__(256) void scan1(const int* __restrict__ cnt,
                                             int* __restrict__ off,
                                             int* __restrict__ bsum) {
    __shared__ int s[256];
    int t = threadIdx.x, i = blockIdx.x * 256 + t;
    int v = (i < NBUCK) ? cnt[i] : 0;
    s[t] = v;
    __syncthreads();
    #pragma unroll
    for (int d = 1; d < 256; d <<= 1) {
        int x = (t >= d) ? s[t - d] : 0;
        __syncthreads();
        s[t] += x;
        __syncthreads();
    }
    if (i < NBUCK) off[i] = s[t] - v;
    if (t == 255) bsum[blockIdx.x] = s[255];
}

__global__ __launch_bounds__(256) void scan2(int* __restrict__ bsum) {
    __shared__ int s[256];
    int t = threadIdx.x;
    int v = (t < NSB) ? bsum[t] : 0;
    s[t] = v;
    __syncthreads();
    #pragma unroll
    for (int d = 1; d < 256; d <<= 1) {
        int x = (t >= d) ? s[t - d] : 0;
        __syncthreads();
        s[t] += x;
        __syncthreads();
    }
    if (t < NSB) bsum[t] = s[t] - v;
}

__global__ __launch_bounds__(256) void scan3(int* __restrict__ off,
                                             const int* __restrict__ bsum) {
    int t = threadIdx.x, i = blockIdx.x * 256 + t;
    if (i < NBUCK) off[i] += bsum[blockIdx.x];
    if (i == 0) off[NBUCK] = TOTP;
}

// ---------------------------------------------------------------------------
// scatter pair -> bucket list; entry packed as (in_row << 8) | out_local
// ---------------------------------------------------------------------------
__global__ __launch_bounds__(256) void scatter_pack(const int* __restrict__ in_idx,
                                                    const int* __restrict__ out_idx,
                                                    const int* __restrict__ off,
                                                    int* __restrict__ cursor,
                                                    int* __restrict__ entries) {
    int p = blockIdx.x * 256 + threadIdx.x;
    if (p >= TOTP) return;
    unsigned k = (unsigned)p / (unsigned)R_PAIRS;
    int orow = out_idx[p];
    int bkt = (orow >> 7) * K_FILT + (int)k;
    int pos = atomicAdd(&cursor[bkt], 1);
    entries[off[bkt] + pos] = (in_idx[p] << 8) | (orow & 127);
}

// ---------------------------------------------------------------------------
// main conv: block owns 128 out rows. Per filter offset kf: B-frags (Wt)
// global->regs once; waves independently grab 16-pair groups; A-frags direct
// from global; 8 MFMA; scatter via ds_add into padded LDS tile. 2 barriers
// total per block. MFMA layouts: A row=lane&15,k=(lane>>4)*8 ;
// C/D col=lane&15, row=(lane>>4)*4+reg (m89-verified).
// ---------------------------------------------------------------------------
__global__ __launch_bounds__(256) void conv_mfma(
    const __bf16* __restrict__ featb,   // [N_ACTIVE][64] bf16
    const __bf16* __restrict__ wtb,     // [K][o][i] bf16 (transposed)
    const float* __restrict__ bias,
    const int* __restrict__ off,        // [NBUCK+1]
    const int* __restrict__ entries,    // [TOTP] packed
    float* __restrict__ out)            // [N_ACTIVE][64] fp32
{
    __shared__ float outT[RB][68];      // 34.8 KB, padded: banks spread
    const int b = blockIdx.x;
    const int t = threadIdx.x;
    const int w = t >> 6;
    const int lane = t & 63;
    const int lrow = lane & 15;         // A-row / B-col / C-col within tile
    const int lkB  = (lane >> 4) * 8;   // k-offset of this lane's fragment
    const int rg4  = (lane >> 4) * 4;   // C-row group base

    {
        float* o = &outT[0][0];
        #pragma unroll
        for (int j = 0; j < 34; ++j) o[j * 256 + t] = 0.f;
    }
    __syncthreads();

    for (int kf = 0; kf < K_FILT; ++kf) {
        int base = off[b * K_FILT + kf];
        int cnt  = off[b * K_FILT + kf + 1] - base;
        if (cnt == 0) continue;

        // B-fragments: 4 col-tiles x 2 k-steps, straight from global (L1/L2 hot)
        bf16x8 bfrag[4][2];
        const __bf16* wk = wtb + kf * 4096;
        #pragma unroll
        for (int n = 0; n < 4; ++n)
            #pragma unroll
            for (int s = 0; s < 2; ++s)
                bfrag[n][s] = *reinterpret_cast<const bf16x8*>(
                    wk + (n * 16 + lrow) * 64 + s * 32 + lkB);

        // waves round-robin over 16-pair groups of this bucket
        for (int g = w; g * 16 < cnt; g += 4) {
            int q0 = g * 16;
            int qa = q0 + lrow;
            int ea = entries[base + (qa < cnt ? qa : 0)];
            int arow = ea >> 8;
            const __bf16* ap = featb + arow * 64 + lkB;
            bf16x8 a0 = *reinterpret_cast<const bf16x8*>(ap);
            bf16x8 a1 = *reinterpret_cast<const bf16x8*>(ap + 32);

            int ors[4];
            #pragma unroll
            for (int r = 0; r < 4; ++r) {
                int q = q0 + rg4 + r;
                int e = entries[base + (q < cnt ? q : 0)];
                ors[r] = e & 127;
            }

            f32x4 acc[4];
            #pragma unroll
            for (int n = 0; n < 4; ++n) {
                acc[n] = __builtin_amdgcn_mfma_f32_16x16x32_bf16(
                    a0, bfrag[n][0], (f32x4){0.f, 0.f, 0.f, 0.f}, 0, 0, 0);
                acc[n] = __builtin_amdgcn_mfma_f32_16x16x32_bf16(
                    a1, bfrag[n][1], acc[n], 0, 0, 0);
            }

            #pragma unroll
            for (int r = 0; r < 4; ++r) {
                if (q0 + rg4 + r < cnt) {
                    #pragma unroll
                    for (int n = 0; n < 4; ++n)
                        atomicAdd(&outT[ors[r]][n * 16 + lrow], acc[n][r]);
                }
            }
        }
    }

    __syncthreads();
    const int rowBase = b * RB;
    #pragma unroll
    for (int j = 0; j < 8; ++j) {
        int idx = j * 1024 + t * 4;
        int r = idx >> 6, c = idx & 63;
        int gr = rowBase + r;
        if (gr < N_ACTIVE) {
            float4 bv = *reinterpret_cast<const float4*>(&bias[c]);
            float4 v  = *reinterpret_cast<const float4*>(&outT[r][c]);
            float4 s4 = {v.x + bv.x, v.y + bv.y, v.z + bv.z, v.w + bv.w};
            *reinterpret_cast<float4*>(&out[gr * 64 + c]) = s4;
        }
    }
}

extern "C" void kernel_launch(void* const* d_in, const int* in_sizes, int n_in,
                              void* d_out, int out_size, void* d_ws, size_t ws_size,
                              hipStream_t stream) {
    const float* feat    = (const float*)d_in[0];
    const float* weight  = (const float*)d_in[1];
    const float* bias    = (const float*)d_in[2];
    const int*   in_idx  = (const int*)d_in[3];
    const int*   out_idx = (const int*)d_in[4];
    float* out = (float*)d_out;

    // ws carve-up (~37.2 MB total)
    char* wsb = (char*)d_ws;
    __bf16* featb = (__bf16*)wsb;                               // 25,600,000 B
    __bf16* wtb   = (__bf16*)(wsb + 25600000);                  //    221,184 B
    int* cnt      = (int*)(wsb + 25600000 + 221184);
    int* cursor   = cnt + NBUCK;
    int* off      = cursor + NBUCK;                             // NBUCK+1
    int* bsum     = off + NBUCK + 1;                            // NSB
    int* entries  = bsum + NSB;                                 // TOTP

    convert_feat<<<dim3((N_ACTIVE * N_IN / 8 + 255) / 256), dim3(256), 0, stream>>>(feat, featb);
    convert_wt<<<dim3(K_FILT), dim3(256), 0, stream>>>(weight, wtb);
    zero_ints<<<dim3((2 * NBUCK + 255) / 256), dim3(256), 0, stream>>>(cnt, 2 * NBUCK);
    hist_kernel<<<dim3((TOTP + 255) / 256), dim3(256), 0, stream>>>(out_idx, cnt);
    scan1<<<dim3(NSB), dim3(256), 0, stream>>>(cnt, off, bsum);
    scan2<<<dim3(1), dim3(256), 0, stream>>>(bsum);
    scan3<<<dim3(NSB), dim3(256), 0, stream>>>(off, bsum);
    scatter_pack<<<dim3((TOTP + 255) / 256), dim3(256), 0, stream>>>(in_idx, out_idx, off, cursor, entries);
    conv_mfma<<<dim3(NB), dim3(256), 0, stream>>>(featb, wtb, bias, off, entries, out);
}

// Round 4
// 1252.479 us; speedup vs baseline: 1.8569x; 1.0331x over previous
//
#include <hip/hip_runtime.h>

#define N_ACTIVE 200000
#define N_IN 64
#define N_OUT 64
#define K_FILT 27
#define R_PAIRS 100000
#define TOTP (K_FILT * R_PAIRS)          // 2,700,000
#define RB 96                            // output rows per block
#define NB ((N_ACTIVE + RB - 1) / RB)    // 2084
#define NBUCK (NB * K_FILT)              // 56,268
#define NSB ((NBUCK + 255) / 256)        // 220

typedef __bf16 bf16x8 __attribute__((ext_vector_type(8)));
typedef float f32x4 __attribute__((ext_vector_type(4)));

// ---------------------------------------------------------------------------
// features fp32 -> bf16
// ---------------------------------------------------------------------------
__global__ __launch_bounds__(256) void convert_feat(const float* __restrict__ f,
                                                    __bf16* __restrict__ fb) {
    int i = blockIdx.x * 256 + threadIdx.x;
    if (i >= N_ACTIVE * N_IN / 8) return;
    const float4* src = reinterpret_cast<const float4*>(f) + 2 * i;
    float4 v0 = src[0], v1 = src[1];
    bf16x8 o;
    o[0] = (__bf16)v0.x; o[1] = (__bf16)v0.y; o[2] = (__bf16)v0.z; o[3] = (__bf16)v0.w;
    o[4] = (__bf16)v1.x; o[5] = (__bf16)v1.y; o[6] = (__bf16)v1.z; o[7] = (__bf16)v1.w;
    reinterpret_cast<bf16x8*>(fb)[i] = o;
}

// ---------------------------------------------------------------------------
// weight fp32 [k][i][o] -> bf16 transposed Wt[k][o][i]
// ---------------------------------------------------------------------------
__global__ __launch_bounds__(256) void convert_wt(const float* __restrict__ wsrc,
                                                  __bf16* __restrict__ wt) {
    int kf = blockIdx.x, t = threadIdx.x;
    const float* wk = wsrc + kf * 4096;
    __bf16* wo = wt + kf * 4096;
    int o = t >> 2, i0 = (t & 3) * 16;
    bf16x8 a, b;
    #pragma unroll
    for (int j = 0; j < 8; ++j) a[j] = (__bf16)wk[(i0 + j) * 64 + o];
    #pragma unroll
    for (int j = 0; j < 8; ++j) b[j] = (__bf16)wk[(i0 + 8 + j) * 64 + o];
    *reinterpret_cast<bf16x8*>(wo + o * 64 + i0) = a;
    *reinterpret_cast<bf16x8*>(wo + o * 64 + i0 + 8) = b;
}

__global__ __launch_bounds__(256) void zero_ints(int* __restrict__ p, int n) {
    int i = blockIdx.x * 256 + threadIdx.x;
    if (i < n) p[i] = 0;
}

__global__ __launch_bounds__(256) void hist_kernel(const int* __restrict__ out_idx,
                                                   int* __restrict__ cnt) {
    int p = blockIdx.x * 256 + threadIdx.x;
    if (p >= TOTP) return;
    unsigned k = (unsigned)p / (unsigned)R_PAIRS;
    int b = (out_idx[p] / RB) * K_FILT + (int)k;
    atomicAdd(&cnt[b], 1);
}

// ---- hierarchical exclusive scan over NBUCK counters ----
__global__ __launch_bounds__(256) void scan1(const int* __restrict__ cnt,
                                             int* __restrict__ off,
                                             int* __restrict__ bsum) {
    __shared__ int s[256];
    int t = threadIdx.x, i = blockIdx.x * 256 + t;
    int v = (i < NBUCK) ? cnt[i] : 0;
    s[t] = v;
    __syncthreads();
    #pragma unroll
    for (int d = 1; d < 256; d <<= 1) {
        int x = (t >= d) ? s[t - d] : 0;
        __syncthreads();
        s[t] += x;
        __syncthreads();
    }
    if (i < NBUCK) off[i] = s[t] - v;
    if (t == 255) bsum[blockIdx.x] = s[255];
}

__global__ __launch_bounds__(256) void scan2(int* __restrict__ bsum) {
    __shared__ int s[256];
    int t = threadIdx.x;
    int v = (t < NSB) ? bsum[t] : 0;
    s[t] = v;
    __syncthreads();
    #pragma unroll
    for (int d = 1; d < 256; d <<= 1) {
        int x = (t >= d) ? s[t - d] : 0;
        __syncthreads();
        s[t] += x;
        __syncthreads();
    }
    if (t < NSB) bsum[t] = s[t] - v;
}

__global__ __launch_bounds__(256) void scan3(int* __restrict__ off,
                                             const int* __restrict__ bsum) {
    int t = threadIdx.x, i = blockIdx.x * 256 + t;
    if (i < NBUCK) off[i] += bsum[blockIdx.x];
    if (i == 0) off[NBUCK] = TOTP;
}

// ---------------------------------------------------------------------------
// scatter pair -> bucket list; entry packed as (in_row << 7) | out_local
// ---------------------------------------------------------------------------
__global__ __launch_bounds__(256) void scatter_pack(const int* __restrict__ in_idx,
                                                    const int* __restrict__ out_idx,
                                                    const int* __restrict__ off,
                                                    int* __restrict__ cursor,
                                                    int* __restrict__ entries) {
    int p = blockIdx.x * 256 + threadIdx.x;
    if (p >= TOTP) return;
    unsigned k = (unsigned)p / (unsigned)R_PAIRS;
    int orow = out_idx[p];
    int rg = orow / RB;
    int bkt = rg * K_FILT + (int)k;
    int pos = atomicAdd(&cursor[bkt], 1);
    entries[off[bkt] + pos] = (in_idx[p] << 7) | (orow - rg * RB);
}

// ---------------------------------------------------------------------------
// conv: block owns 96 out rows; wave w handles buckets kf = w, w+4, ...
// Per bucket: ONE coalesced 64-entry load, ds_bpermute to distribute,
// 6-8 independent A-gather loads in flight, 8 MFMA per 16-pair group,
// ds_add scatter into LDS out tile. MFMA layouts as r3 (verified).
// ---------------------------------------------------------------------------
__global__ __launch_bounds__(256) void conv_mfma(
    const __bf16* __restrict__ featb,   // [N_ACTIVE][64] bf16
    const __bf16* __restrict__ wtb,     // [K][o][i] bf16 transposed
    const float* __restrict__ bias,
    const int* __restrict__ off,        // [NBUCK+1]
    const int* __restrict__ entries,    // [TOTP] packed
    float* __restrict__ out)            // [N_ACTIVE][64] fp32
{
    __shared__ float outT[RB][68];      // 26,112 B
    const int b = blockIdx.x;
    const int t = threadIdx.x;
    const int w = t >> 6;
    const int lane = t & 63;
    const int lrow = lane & 15;
    const int lkB  = (lane >> 4) * 8;
    const int rg4  = (lane >> 4) * 4;

    {
        float4 z = {0.f, 0.f, 0.f, 0.f};
        float4* o4 = reinterpret_cast<float4*>(&outT[0][0]);
        #pragma unroll
        for (int j = 0; j < 7; ++j) {
            int i = j * 256 + t;
            if (i < RB * 68 / 4) o4[i] = z;
        }
    }
    __syncthreads();

    const int bK = b * K_FILT;
    for (int kf = w; kf < K_FILT; kf += 4) {
        int base = off[bK + kf];
        int cnt  = off[bK + kf + 1] - base;
        if (cnt <= 0) continue;

        // B fragments from global (L1/L2-hot): 4 col-tiles x 2 k-steps
        bf16x8 bfrag[4][2];
        const __bf16* wk = wtb + kf * 4096;
        #pragma unroll
        for (int n = 0; n < 4; ++n)
            #pragma unroll
            for (int s = 0; s < 2; ++s)
                bfrag[n][s] = *reinterpret_cast<const bf16x8*>(
                    wk + (n * 16 + lrow) * 64 + s * 32 + lkB);

        for (int c0 = 0; c0 < cnt; c0 += 64) {
            int rem = cnt - c0; if (rem > 64) rem = 64;
            int eaddr = base + c0 + lane;
            int v_ent = entries[eaddr < TOTP ? eaddr : TOTP - 1];  // coalesced
            int ngr = (rem + 15) >> 4;

            for (int gi = 0; gi < ngr; ++gi) {
                // distribute entries via cross-lane pull (LDS pipe, no gather)
                int ea = __builtin_amdgcn_ds_bpermute((gi * 16 + lrow) * 4, v_ent);
                int arow = ea >> 7;
                const __bf16* ap = featb + arow * 64 + lkB;
                bf16x8 a0 = *reinterpret_cast<const bf16x8*>(ap);
                bf16x8 a1 = *reinterpret_cast<const bf16x8*>(ap + 32);

                int ors[4];
                #pragma unroll
                for (int r = 0; r < 4; ++r) {
                    int eo = __builtin_amdgcn_ds_bpermute((gi * 16 + rg4 + r) * 4, v_ent);
                    ors[r] = eo & 127;
                }

                f32x4 acc[4];
                #pragma unroll
                for (int n = 0; n < 4; ++n) {
                    acc[n] = __builtin_amdgcn_mfma_f32_16x16x32_bf16(
                        a0, bfrag[n][0], (f32x4){0.f, 0.f, 0.f, 0.f}, 0, 0, 0);
                    acc[n] = __builtin_amdgcn_mfma_f32_16x16x32_bf16(
                        a1, bfrag[n][1], acc[n], 0, 0, 0);
                }

                #pragma unroll
                for (int r = 0; r < 4; ++r) {
                    if (c0 + gi * 16 + rg4 + r < cnt) {
                        #pragma unroll
                        for (int n = 0; n < 4; ++n)
                            atomicAdd(&outT[ors[r]][n * 16 + lrow], acc[n][r]);
                    }
                }
            }
        }
    }

    __syncthreads();
    const int rowBase = b * RB;
    #pragma unroll
    for (int j = 0; j < 6; ++j) {
        int idx = j * 1024 + t * 4;
        int r = idx >> 6, c = idx & 63;
        int gr = rowBase + r;
        if (gr < N_ACTIVE) {
            float4 bv = *reinterpret_cast<const float4*>(&bias[c]);
            float4 v  = *reinterpret_cast<const float4*>(&outT[r][c]);
            float4 s4 = {v.x + bv.x, v.y + bv.y, v.z + bv.z, v.w + bv.w};
            *reinterpret_cast<float4*>(&out[gr * 64 + c]) = s4;
        }
    }
}

extern "C" void kernel_launch(void* const* d_in, const int* in_sizes, int n_in,
                              void* d_out, int out_size, void* d_ws, size_t ws_size,
                              hipStream_t stream) {
    const float* feat    = (const float*)d_in[0];
    const float* weight  = (const float*)d_in[1];
    const float* bias    = (const float*)d_in[2];
    const int*   in_idx  = (const int*)d_in[3];
    const int*   out_idx = (const int*)d_in[4];
    float* out = (float*)d_out;

    char* wsb = (char*)d_ws;
    __bf16* featb = (__bf16*)wsb;                               // 25,600,000 B
    __bf16* wtb   = (__bf16*)(wsb + 25600000);                  //    221,184 B
    int* cnt      = (int*)(wsb + 25600000 + 221184);
    int* cursor   = cnt + NBUCK;
    int* off      = cursor + NBUCK;                             // NBUCK+1
    int* bsum     = off + NBUCK + 1;                            // NSB
    int* entries  = bsum + NSB;                                 // TOTP

    convert_feat<<<dim3((N_ACTIVE * N_IN / 8 + 255) / 256), dim3(256), 0, stream>>>(feat, featb);
    convert_wt<<<dim3(K_FILT), dim3(256), 0, stream>>>(weight, wtb);
    zero_ints<<<dim3((2 * NBUCK + 255) / 256), dim3(256), 0, stream>>>(cnt, 2 * NBUCK);
    hist_kernel<<<dim3((TOTP + 255) / 256), dim3(256), 0, stream>>>(out_idx, cnt);
    scan1<<<dim3(NSB), dim3(256), 0, stream>>>(cnt, off, bsum);
    scan2<<<dim3(1), dim3(256), 0, stream>>>(bsum);
    scan3<<<dim3(NSB), dim3(256), 0, stream>>>(off, bsum);
    scatter_pack<<<dim3((TOTP + 255) / 256), dim3(256), 0, stream>>>(in_idx, out_idx, off, cursor, entries);
    conv_mfma<<<dim3(NB), dim3(256), 0, stream>>>(featb, wtb, bias, off, entries, out);
}

// Round 5
// 1249.322 us; speedup vs baseline: 1.8616x; 1.0025x over previous
//
#include <hip/hip_runtime.h>

#define N_ACTIVE 200000
#define N_IN 64
#define N_OUT 64
#define K_FILT 27
#define R_PAIRS 100000
#define TOTP (K_FILT * R_PAIRS)          // 2,700,000
#define RB 96                            // output rows per block
#define NB ((N_ACTIVE + RB - 1) / RB)    // 2084
#define NBUCK (NB * K_FILT)              // 56,268
#define NSB ((NBUCK + 255) / 256)        // 220
#define ELDS 2048                        // staged entries per block (mean 1296)

#define CF_BLOCKS (N_ACTIVE * N_IN / 8 / 256)    // 6250 convert_feat blocks
#define CW_BLOCKS K_FILT                          // 27 convert_wt blocks
#define HI_BLOCKS ((TOTP + 255) / 256)            // 10547 hist blocks

typedef __bf16 bf16x8 __attribute__((ext_vector_type(8)));
typedef float f32x4 __attribute__((ext_vector_type(4)));

__global__ __launch_bounds__(256) void zero_ints(int* __restrict__ p, int n) {
    int i = blockIdx.x * 256 + threadIdx.x;
    if (i < n) p[i] = 0;
}

// ---------------------------------------------------------------------------
// fused prep: convert_feat | convert_wt | hist, branched on blockIdx ranges
// ---------------------------------------------------------------------------
__global__ __launch_bounds__(256) void prep_fused(
    const float* __restrict__ feat, __bf16* __restrict__ featb,
    const float* __restrict__ wsrc, __bf16* __restrict__ wt,
    const int* __restrict__ out_idx, int* __restrict__ cnt)
{
    int bb = blockIdx.x, t = threadIdx.x;
    if (bb < CF_BLOCKS) {
        // features fp32 -> bf16 (nt read of fp32; NORMAL write: want L3-hot)
        int i = bb * 256 + t;
        const f32x4* src = reinterpret_cast<const f32x4*>(feat) + 2 * (size_t)i;
        f32x4 v0 = __builtin_nontemporal_load(src);
        f32x4 v1 = __builtin_nontemporal_load(src + 1);
        bf16x8 o;
        o[0] = (__bf16)v0[0]; o[1] = (__bf16)v0[1]; o[2] = (__bf16)v0[2]; o[3] = (__bf16)v0[3];
        o[4] = (__bf16)v1[0]; o[5] = (__bf16)v1[1]; o[6] = (__bf16)v1[2]; o[7] = (__bf16)v1[3];
        reinterpret_cast<bf16x8*>(featb)[i] = o;
    } else if (bb < CF_BLOCKS + CW_BLOCKS) {
        // weight fp32 [k][i][o] -> bf16 transposed Wt[k][o][i]
        int kf = bb - CF_BLOCKS;
        const float* wk = wsrc + kf * 4096;
        __bf16* wo = wt + kf * 4096;
        int o = t >> 2, i0 = (t & 3) * 16;
        bf16x8 a, b;
        #pragma unroll
        for (int j = 0; j < 8; ++j) a[j] = (__bf16)wk[(i0 + j) * 64 + o];
        #pragma unroll
        for (int j = 0; j < 8; ++j) b[j] = (__bf16)wk[(i0 + 8 + j) * 64 + o];
        *reinterpret_cast<bf16x8*>(wo + o * 64 + i0) = a;
        *reinterpret_cast<bf16x8*>(wo + o * 64 + i0 + 8) = b;
    } else {
        // histogram
        int p = (bb - CF_BLOCKS - CW_BLOCKS) * 256 + t;
        if (p < TOTP) {
            unsigned k = (unsigned)p / (unsigned)R_PAIRS;
            int b = (out_idx[p] / RB) * K_FILT + (int)k;
            atomicAdd(&cnt[b], 1);
        }
    }
}

// ---- hierarchical exclusive scan over NBUCK counters ----
__global__ __launch_bounds__(256) void scan1(const int* __restrict__ cnt,
                                             int* __restrict__ off,
                                             int* __restrict__ bsum) {
    __shared__ int s[256];
    int t = threadIdx.x, i = blockIdx.x * 256 + t;
    int v = (i < NBUCK) ? cnt[i] : 0;
    s[t] = v;
    __syncthreads();
    #pragma unroll
    for (int d = 1; d < 256; d <<= 1) {
        int x = (t >= d) ? s[t - d] : 0;
        __syncthreads();
        s[t] += x;
        __syncthreads();
    }
    if (i < NBUCK) off[i] = s[t] - v;
    if (t == 255) bsum[blockIdx.x] = s[255];
}

__global__ __launch_bounds__(256) void scan2(int* __restrict__ bsum) {
    __shared__ int s[256];
    int t = threadIdx.x;
    int v = (t < NSB) ? bsum[t] : 0;
    s[t] = v;
    __syncthreads();
    #pragma unroll
    for (int d = 1; d < 256; d <<= 1) {
        int x = (t >= d) ? s[t - d] : 0;
        __syncthreads();
        s[t] += x;
        __syncthreads();
    }
    if (t < NSB) bsum[t] = s[t] - v;
}

__global__ __launch_bounds__(256) void scan3(int* __restrict__ off,
                                             const int* __restrict__ bsum) {
    int t = threadIdx.x, i = blockIdx.x * 256 + t;
    if (i < NBUCK) off[i] += bsum[blockIdx.x];
    if (i == 0) off[NBUCK] = TOTP;
}

// ---------------------------------------------------------------------------
// scatter pair -> bucket list; entry packed as (in_row << 7) | out_local
// ---------------------------------------------------------------------------
__global__ __launch_bounds__(256) void scatter_pack(const int* __restrict__ in_idx,
                                                    const int* __restrict__ out_idx,
                                                    const int* __restrict__ off,
                                                    int* __restrict__ cursor,
                                                    int* __restrict__ entries) {
    int p = blockIdx.x * 256 + threadIdx.x;
    if (p >= TOTP) return;
    unsigned k = (unsigned)p / (unsigned)R_PAIRS;
    int orow = out_idx[p];
    int iv = __builtin_nontemporal_load(&in_idx[p]);
    int rg = orow / RB;
    int bkt = rg * K_FILT + (int)k;
    int pos = atomicAdd(&cursor[bkt], 1);
    entries[off[bkt] + pos] = (iv << 7) | (orow - rg * RB);
}

// ---------------------------------------------------------------------------
// conv: block owns 96 out rows. Block's 27 buckets are CONTIGUOUS in entries
// -> stage them all in LDS once (coalesced nt-loads). Wave w does buckets
// kf = w, w+4, ...; per 16-pair group: entries from LDS, A-frags gathered
// from global featb (temporal: want L3 retention), 8 MFMA, ds_add scatter.
// MFMA layouts as r3/r4 (verified).
// ---------------------------------------------------------------------------
__global__ __launch_bounds__(256) void conv_mfma(
    const __bf16* __restrict__ featb,   // [N_ACTIVE][64] bf16
    const __bf16* __restrict__ wtb,     // [K][o][i] bf16 transposed
    const float* __restrict__ bias,
    const int* __restrict__ off,        // [NBUCK+1]
    const int* __restrict__ entries,    // [TOTP] packed
    float* __restrict__ out)            // [N_ACTIVE][64] fp32
{
    __shared__ float outT[RB][68];      // 26,112 B
    __shared__ int   eLds[ELDS];        //  8,192 B
    __shared__ int   sOff[K_FILT + 1];

    const int b = blockIdx.x;
    const int t = threadIdx.x;
    const int w = t >> 6;
    const int lane = t & 63;
    const int lrow = lane & 15;
    const int lkB  = (lane >> 4) * 8;
    const int rg4  = (lane >> 4) * 4;
    const int bK = b * K_FILT;

    if (t < K_FILT + 1) sOff[t] = off[bK + t];

    {   // zero out tile
        f32x4 z = {0.f, 0.f, 0.f, 0.f};
        f32x4* o4 = reinterpret_cast<f32x4*>(&outT[0][0]);
        #pragma unroll
        for (int j = 0; j < 7; ++j) {
            int i = j * 256 + t;
            if (i < RB * 68 / 4) o4[i] = z;
        }
    }

    const int blockStart = off[bK];                 // uniform
    const int total = off[bK + K_FILT] - blockStart;
    const int stged = total < ELDS ? total : ELDS;
    for (int i = t; i < stged; i += 256)
        eLds[i] = __builtin_nontemporal_load(&entries[blockStart + i]);
    __syncthreads();

    for (int kf = w; kf < K_FILT; kf += 4) {
        int gbase = sOff[kf] - blockStart;
        int cnt   = sOff[kf + 1] - sOff[kf];
        if (cnt <= 0) continue;

        // B fragments from global (L2-hot, 216 KB total): 4 col-tiles x 2 k-steps
        bf16x8 bfrag[4][2];
        const __bf16* wk = wtb + kf * 4096;
        #pragma unroll
        for (int n = 0; n < 4; ++n)
            #pragma unroll
            for (int s = 0; s < 2; ++s)
                bfrag[n][s] = *reinterpret_cast<const bf16x8*>(
                    wk + (n * 16 + lrow) * 64 + s * 32 + lkB);

        int ngr = (cnt + 15) >> 4;
        for (int gi = 0; gi < ngr; ++gi) {
            int pa = gi * 16 + lrow;
            int ja = gbase + (pa < cnt ? pa : 0);
            int ea = (ja < stged) ? eLds[ja]
                                  : __builtin_nontemporal_load(&entries[blockStart + ja]);
            int arow = ea >> 7;
            const __bf16* ap = featb + arow * 64 + lkB;   // temporal loads
            bf16x8 a0 = *reinterpret_cast<const bf16x8*>(ap);
            bf16x8 a1 = *reinterpret_cast<const bf16x8*>(ap + 32);

            int ors[4];
            #pragma unroll
            for (int r = 0; r < 4; ++r) {
                int q = gi * 16 + rg4 + r;
                int jq = gbase + (q < cnt ? q : 0);
                int eo = (jq < stged) ? eLds[jq]
                                      : __builtin_nontemporal_load(&entries[blockStart + jq]);
                ors[r] = eo & 127;
            }

            f32x4 acc[4];
            #pragma unroll
            for (int n = 0; n < 4; ++n) {
                acc[n] = __builtin_amdgcn_mfma_f32_16x16x32_bf16(
                    a0, bfrag[n][0], (f32x4){0.f, 0.f, 0.f, 0.f}, 0, 0, 0);
                acc[n] = __builtin_amdgcn_mfma_f32_16x16x32_bf16(
                    a1, bfrag[n][1], acc[n], 0, 0, 0);
            }

            #pragma unroll
            for (int r = 0; r < 4; ++r) {
                if (gi * 16 + rg4 + r < cnt) {
                    #pragma unroll
                    for (int n = 0; n < 4; ++n)
                        atomicAdd(&outT[ors[r]][n * 16 + lrow], acc[n][r]);
                }
            }
        }
    }

    __syncthreads();
    const int rowBase = b * RB;
    #pragma unroll
    for (int j = 0; j < 6; ++j) {
        int idx = j * 1024 + t * 4;
        int r = idx >> 6, c = idx & 63;
        int gr = rowBase + r;
        if (gr < N_ACTIVE) {
            f32x4 bv = *reinterpret_cast<const f32x4*>(&bias[c]);
            f32x4 v  = *reinterpret_cast<const f32x4*>(&outT[r][c]);
            v += bv;
            __builtin_nontemporal_store(v, reinterpret_cast<f32x4*>(&out[gr * 64 + c]));
        }
    }
}

extern "C" void kernel_launch(void* const* d_in, const int* in_sizes, int n_in,
                              void* d_out, int out_size, void* d_ws, size_t ws_size,
                              hipStream_t stream) {
    const float* feat    = (const float*)d_in[0];
    const float* weight  = (const float*)d_in[1];
    const float* bias    = (const float*)d_in[2];
    const int*   in_idx  = (const int*)d_in[3];
    const int*   out_idx = (const int*)d_in[4];
    float* out = (float*)d_out;

    char* wsb = (char*)d_ws;
    __bf16* featb = (__bf16*)wsb;                               // 25,600,000 B
    __bf16* wtb   = (__bf16*)(wsb + 25600000);                  //    221,184 B
    int* cnt      = (int*)(wsb + 25600000 + 221184);
    int* cursor   = cnt + NBUCK;
    int* off      = cursor + NBUCK;                             // NBUCK+1
    int* bsum     = off + NBUCK + 1;                            // NSB
    int* entries  = bsum + NSB;                                 // TOTP

    zero_ints<<<dim3((2 * NBUCK + 255) / 256), dim3(256), 0, stream>>>(cnt, 2 * NBUCK);
    prep_fused<<<dim3(CF_BLOCKS + CW_BLOCKS + HI_BLOCKS), dim3(256), 0, stream>>>(
        feat, featb, weight, wtb, out_idx, cnt);
    scan1<<<dim3(NSB), dim3(256), 0, stream>>>(cnt, off, bsum);
    scan2<<<dim3(1), dim3(256), 0, stream>>>(bsum);
    scan3<<<dim3(NSB), dim3(256), 0, stream>>>(off, bsum);
    scatter_pack<<<dim3((TOTP + 255) / 256), dim3(256), 0, stream>>>(in_idx, out_idx, off, cursor, entries);
    conv_mfma<<<dim3(NB), dim3(256), 0, stream>>>(featb, wtb, bias, off, entries, out);
}